// Round 18
// baseline (73.103 us; speedup 1.0000x reference)
//
#include <hip/hip_runtime.h>

// B=32, L=512, D=1024; 7 linear experts + identity, routed per token.
// K1 prep_k: block 0 = route (ballot, batched); 1..448 = W f32->bf16;
//            449..1472 = A rows (identity copy / convert, token order).
// K2 gemm_k: faithful m201-style 8-phase schedule. 256 blocks (1/CU),
//   256x256 tile, 8 waves (2Mx4N), BK=64, XOR-swizzled LDS, 2 tile-buffers.
//   Per K-tile: 4 phases {ds_read quadrant (12/4/8/4 b128) -> stage ONE
//   half-tile (2 gloads/thr) -> barrier -> lgkm0+schedbar -> setprio ->
//   16 MFMA -> barrier}. Half-tiles: A-mq = rows bit6=mq, B-np = cols
//   bit5=np, so each region's last reader precedes its overwrite.
//   Staging runs 3 half-tiles ahead; single counted vmcnt(6) at ph4
//   (vmcnt(0) at tail). Quadrant order (m0,n0)(m0,n1)(m1,n1)(m1,n0).

#define NTOK 16384
#define DDIM 1024
#define NEXP 7
#define BM 256
#define BN 256
#define BK 64
#define NKT (DDIM / BK)

#define WI_OFFS   16          // [8]; offs[7] = nlin
#define WI_NTILES 32
#define WI_TABLE  64          // [72][2] {expert, crow0}
#define WI_CTOK   512         // [0,nlin): slot -> token
#define WS_ABF_B  1048576                       // 32 MB bf16 A (token order)
#define WS_WBF_B  (WS_ABF_B + NTOK * DDIM * 2)  // 14 MB bf16 W

typedef __attribute__((ext_vector_type(8))) short short8;
typedef __attribute__((ext_vector_type(4))) float f32x4;

__device__ __forceinline__ unsigned short f2bf(float f) {
    unsigned u = __float_as_uint(f);
    u += 0x7fff + ((u >> 16) & 1);
    return (unsigned short)(u >> 16);
}

__device__ __forceinline__ void gload16(const void* g, void* l) {
    __builtin_amdgcn_global_load_lds(
        (const __attribute__((address_space(1))) void*)g,
        (__attribute__((address_space(3))) void*)l, 16, 0, 0);
}

__global__ __launch_bounds__(1024) void prep_k(
    const int* __restrict__ type, int* __restrict__ wsi,
    const float* __restrict__ W, unsigned short* __restrict__ Wbf,
    const float* __restrict__ A, unsigned short* __restrict__ Abf,
    float* __restrict__ out) {
    const int bid = blockIdx.x, tid = threadIdx.x;
    if (bid == 0) {
        __shared__ int h[16][8];
        __shared__ int base2[16][8];
        const int wave = tid >> 6, lane = tid & 63;
        const unsigned long long lt = (1ULL << lane) - 1;

        const int4* tsrc = (const int4*)(type + tid * 16);
        int4 v0 = tsrc[0], v1 = tsrc[1], v2 = tsrc[2], v3 = tsrc[3];
        int kv[16] = { v0.x, v0.y, v0.z, v0.w, v1.x, v1.y, v1.z, v1.w,
                       v2.x, v2.y, v2.z, v2.w, v3.x, v3.y, v3.z, v3.w };

        int cnt[8];
#pragma unroll
        for (int e = 0; e < 8; ++e) cnt[e] = 0;
#pragma unroll
        for (int i = 0; i < 16; ++i) {
#pragma unroll
            for (int e = 1; e < 8; ++e)
                cnt[e] += __popcll(__ballot(kv[i] == e));
        }
        if (lane == 0) {
#pragma unroll
            for (int e = 0; e < 8; ++e) h[wave][e] = cnt[e];
        }
        __syncthreads();

        if (tid == 0) {
            int acc = 0, t = 0;
            for (int e = 0; e < NEXP; ++e) {
                wsi[WI_OFFS + e] = acc;
                int run = acc;
                for (int w = 0; w < 16; ++w) { base2[w][e + 1] = run; run += h[w][e + 1]; }
                int nt = (run - acc + BM - 1) >> 8;
                for (int i = 0; i < nt; ++i) {
                    wsi[WI_TABLE + 2 * t] = e;
                    wsi[WI_TABLE + 2 * t + 1] = acc + i * BM;
                    ++t;
                }
                acc = run;
            }
            wsi[WI_OFFS + NEXP] = acc;
            wsi[WI_NTILES] = t;
        }
        __syncthreads();

        int rb[8];
#pragma unroll
        for (int e = 1; e < 8; ++e) rb[e] = base2[wave][e];
#pragma unroll
        for (int i = 0; i < 16; ++i) {
            int k = kv[i];
            int pos = -1;
#pragma unroll
            for (int e = 1; e < 8; ++e) {
                unsigned long long m = __ballot(k == e);
                int p = rb[e] + __popcll(m & lt);
                pos = (k == e) ? p : pos;
                rb[e] += __popcll(m);
            }
            if (k > 0) wsi[WI_CTOK + pos] = tid * 16 + i;
        }
    } else if (bid <= 448) {
        size_t i = ((size_t)(bid - 1) * 1024 + tid) * 16;
        const float4* src = (const float4*)(W + i);
        float4 v0 = src[0], v1 = src[1], v2 = src[2], v3 = src[3];
        short8 h0, h1;
        h0[0]=f2bf(v0.x); h0[1]=f2bf(v0.y); h0[2]=f2bf(v0.z); h0[3]=f2bf(v0.w);
        h0[4]=f2bf(v1.x); h0[5]=f2bf(v1.y); h0[6]=f2bf(v1.z); h0[7]=f2bf(v1.w);
        h1[0]=f2bf(v2.x); h1[1]=f2bf(v2.y); h1[2]=f2bf(v2.z); h1[3]=f2bf(v2.w);
        h1[4]=f2bf(v3.x); h1[5]=f2bf(v3.y); h1[6]=f2bf(v3.z); h1[7]=f2bf(v3.w);
        *(short8*)(Wbf + i) = h0;
        *(short8*)(Wbf + i + 8) = h1;
    } else {
        const int wave = tid >> 6, lane = tid & 63;
        const int t = (bid - 449) * 16 + wave;
        const float4* src = (const float4*)(A + (size_t)t * DDIM);
        if (type[t] == 0) {
            float4* d = (float4*)(out + (size_t)t * DDIM);
#pragma unroll
            for (int j = 0; j < 4; ++j) d[lane + j * 64] = src[lane + j * 64];
        } else {
            float4 v0 = src[lane * 4 + 0], v1 = src[lane * 4 + 1];
            float4 v2 = src[lane * 4 + 2], v3 = src[lane * 4 + 3];
            short8 h0, h1;
            h0[0]=f2bf(v0.x); h0[1]=f2bf(v0.y); h0[2]=f2bf(v0.z); h0[3]=f2bf(v0.w);
            h0[4]=f2bf(v1.x); h0[5]=f2bf(v1.y); h0[6]=f2bf(v1.z); h0[7]=f2bf(v1.w);
            h1[0]=f2bf(v2.x); h1[1]=f2bf(v2.y); h1[2]=f2bf(v2.z); h1[3]=f2bf(v2.w);
            h1[4]=f2bf(v3.x); h1[5]=f2bf(v3.y); h1[6]=f2bf(v3.z); h1[7]=f2bf(v3.w);
            unsigned short* d = Abf + (size_t)t * DDIM + lane * 16;
            *(short8*)d = h0;
            *(short8*)(d + 8) = h1;
        }
    }
}

// ---- 8-phase gemm machinery ----
#define RD_A(AR, MQ)                                                \
    _Pragma("unroll")                                               \
    for (int i = 0; i < 4; ++i) {                                   \
        a[i][0] = *(const short8*)((AR) + ((MQ) * 4 + i) * 2048 + sl0); \
        a[i][1] = *(const short8*)((AR) + ((MQ) * 4 + i) * 2048 + sl1); \
    }

#define RD_B(BR, NP)                                                \
    _Pragma("unroll")                                               \
    for (int n = 0; n < 2; ++n) {                                   \
        b[n][0] = *(const short8*)((BR) + ((NP) * 2 + n) * 2048 + sl0); \
        b[n][1] = *(const short8*)((BR) + ((NP) * 2 + n) * 2048 + sl1); \
    }

#define STG_A(DST, MQ, KTT)                                         \
    gload16(aP[MQ][0] + (KTT) * BK, (char*)(DST) + dA[MQ][0]);      \
    gload16(aP[MQ][1] + (KTT) * BK, (char*)(DST) + dA[MQ][1]);

#define STG_B(DST, NP, KTT)                                         \
    gload16(bP[NP][0] + (KTT) * BK, (char*)(DST) + dB[NP][0]);      \
    gload16(bP[NP][1] + (KTT) * BK, (char*)(DST) + dB[NP][1]);

#define MF_PH(MQ, NP)                                               \
    __builtin_amdgcn_s_barrier();                                   \
    asm volatile("s_waitcnt lgkmcnt(0)" ::: "memory");              \
    __builtin_amdgcn_sched_barrier(0);                              \
    __builtin_amdgcn_s_setprio(1);                                  \
    _Pragma("unroll")                                               \
    for (int i = 0; i < 4; ++i)                                     \
        _Pragma("unroll")                                           \
        for (int n = 0; n < 2; ++n) {                               \
            acc[(MQ)*4+i][(NP)*2+n] = __builtin_amdgcn_mfma_f32_16x16x32_bf16( \
                a[i][0], b[n][0], acc[(MQ)*4+i][(NP)*2+n], 0, 0, 0);\
            acc[(MQ)*4+i][(NP)*2+n] = __builtin_amdgcn_mfma_f32_16x16x32_bf16( \
                a[i][1], b[n][1], acc[(MQ)*4+i][(NP)*2+n], 0, 0, 0);\
        }                                                           \
    __builtin_amdgcn_s_setprio(0);                                  \
    __builtin_amdgcn_s_barrier();

// One K-tile = 4 phases. AR/BR: cur read bases. AD/BD: cur-buf arrays
// (t+2 halves). BDN: other-buf B array (t+1's B-n0).
#define TILE8(AR, BR, AD, BD, BDN, KT)                              \
    do {                                                            \
        short8 a[4][2], b[2][2];                                    \
        RD_A(AR, 0); RD_B(BR, 0);                                   \
        if ((KT) + 1 < NKT) { STG_B(BDN, 0, (KT) + 1); }            \
        MF_PH(0, 0);                                                \
        RD_B(BR, 1);                                                \
        if ((KT) + 2 < NKT) { STG_A(AD, 0, (KT) + 2); }             \
        MF_PH(0, 1);                                                \
        RD_A(AR, 1);                                                \
        if ((KT) + 2 < NKT) { STG_B(BD, 1, (KT) + 2); }             \
        MF_PH(1, 1);                                                \
        RD_B(BR, 0);                                                \
        if ((KT) + 2 < NKT) {                                       \
            STG_A(AD, 1, (KT) + 2);                                 \
            asm volatile("s_waitcnt vmcnt(6)" ::: "memory");        \
        } else {                                                    \
            asm volatile("s_waitcnt vmcnt(0)" ::: "memory");        \
        }                                                           \
        MF_PH(1, 0);                                                \
    } while (0)

__global__ __launch_bounds__(512, 2) void gemm_k(
    const unsigned short* __restrict__ Abf,
    const unsigned short* __restrict__ Wbf,
    const float* __restrict__ bias, float* __restrict__ out,
    const int* __restrict__ wsi) {
    const int bid = blockIdx.x;              // 0..255, 1 per CU
    const int c = bid & 7;                   // XCD
    const int g = bid >> 3;
    const int ntiles = wsi[WI_NTILES];
    const int* offs = wsi + WI_OFFS;
    const int* tab  = wsi + WI_TABLE;
    const int* ctok = wsi + WI_CTOK;
    const int nlin  = offs[NEXP];

    __shared__ unsigned short As0[BM * BK];   // 32 KB each; 2 tile-buffers
    __shared__ unsigned short As1[BM * BK];
    __shared__ unsigned short Bs0[BM * BK];
    __shared__ unsigned short Bs1[BM * BK];

    const int tid = threadIdx.x, lane = tid & 63, wave = tid >> 6;
    const int wr = wave >> 2, wc = wave & 3;     // wave-tile 128x64
    const int lane15 = lane & 15;
    const int l3 = lane >> 3;                    // 0..7
    const int schunk = ((lane & 7) ^ l3) * 8;    // inverse-swizzled src chunk

    const int sl0 = (((lane >> 4)) ^ (lane & 7)) * 16;
    const int sl1 = ((4 | (lane >> 4)) ^ (lane & 7)) * 16;
    const char* aR0 = (const char*)As0 + wr * 16384 + lane15 * 128;
    const char* aR1 = (const char*)As1 + wr * 16384 + lane15 * 128;
    const char* bR0 = (const char*)Bs0 + wc * 8192 + lane15 * 128;
    const char* bR1 = (const char*)Bs1 + wc * 8192 + lane15 * 128;

    // stage dest byte-offsets: A half mq, sub j: rows j*128+mq*64+wave*8
    int dA[2][2], dB[2][2];
#pragma unroll
    for (int mq = 0; mq < 2; ++mq)
#pragma unroll
        for (int j = 0; j < 2; ++j)
            dA[mq][j] = (j * 128 + mq * 64 + wave * 8) * 128;
#pragma unroll
    for (int np = 0; np < 2; ++np)
#pragma unroll
        for (int j = 0; j < 2; ++j)
            dB[np][j] = ((((wave >> 2) + 2 * j) * 64) + np * 32 + (wave & 3) * 8) * 128;

    for (int rep = 0; rep < 2; ++rep) {
        const int q4 = g + 32 * rep;
        const int ty = (q4 >> 2) * 8 + c;
        const int tx = q4 & 3;
        if (ty >= ntiles) break;

        const int e     = tab[2 * ty];
        const int crow0 = tab[2 * ty + 1];
        const int nend  = offs[e + 1];
        const int col0  = tx * BN;
        const unsigned short* Wb = Wbf + (size_t)e * DDIM * DDIM;

        // stage source pointers (per-lane)
        const unsigned short* aP[2][2];
        const unsigned short* bP[2][2];
#pragma unroll
        for (int mq = 0; mq < 2; ++mq)
#pragma unroll
            for (int j = 0; j < 2; ++j) {
                int r = j * 128 + mq * 64 + wave * 8 + l3;
                aP[mq][j] = Abf + (size_t)ctok[min(crow0 + r, nlin - 1)] * DDIM + schunk;
                int cc = ((wave >> 2) + 2 * j) * 64 + mq * 32 + (wave & 3) * 8 + l3;
                bP[mq][j] = Wb + (size_t)(col0 + cc) * DDIM + schunk;
            }

        f32x4 acc[8][4];
#pragma unroll
        for (int m = 0; m < 8; ++m)
#pragma unroll
            for (int n = 0; n < 4; ++n) acc[m][n] = (f32x4){0.f, 0.f, 0.f, 0.f};

        // prologue: tile0 (8 loads) + tile1 minus B-n0 (6 loads)
        STG_A(As0, 0, 0); STG_B(Bs0, 0, 0); STG_B(Bs0, 1, 0); STG_A(As0, 1, 0);
        STG_A(As1, 0, 1); STG_B(Bs1, 1, 1); STG_A(As1, 1, 1);
        asm volatile("s_waitcnt vmcnt(6)" ::: "memory");   // tile0 resident
        __builtin_amdgcn_s_barrier();

        for (int kt2 = 0; kt2 < NKT / 2; ++kt2) {
            TILE8(aR0, bR0, As0, Bs0, Bs1, 2 * kt2);
            TILE8(aR1, bR1, As1, Bs1, Bs0, 2 * kt2 + 1);
        }

        // epilogue: bias + gathered store (C/D: col=lane&15, row=(lane>>4)*4+r)
        const int crow4 = (lane >> 4) * 4;
        float bv[4];
#pragma unroll
        for (int n = 0; n < 4; ++n)
            bv[n] = bias[e * DDIM + col0 + wc * 64 + n * 16 + lane15];

#pragma unroll
        for (int m = 0; m < 8; ++m) {
#pragma unroll
            for (int r = 0; r < 4; ++r) {
                int gr = crow0 + wr * 128 + m * 16 + crow4 + r;
                if (gr >= nend) continue;
                int tok = ctok[gr];
                float* orow = out + (size_t)tok * DDIM + col0 + wc * 64 + lane15;
#pragma unroll
                for (int n = 0; n < 4; ++n)
                    orow[n * 16] = acc[m][n][r] + bv[n];
            }
        }
        __builtin_amdgcn_s_barrier();   // LDS quiesced before next rep's stage
    }
}

extern "C" void kernel_launch(void* const* d_in, const int* in_sizes, int n_in,
                              void* d_out, int out_size, void* d_ws, size_t ws_size,
                              hipStream_t stream) {
    const float* actions = (const float*)d_in[0];
    const int*   atype   = (const int*)d_in[1];
    const float* W       = (const float*)d_in[2];
    const float* bias    = (const float*)d_in[3];
    float* out = (float*)d_out;

    int* wsi = (int*)d_ws;
    unsigned short* Abf = (unsigned short*)((char*)d_ws + WS_ABF_B);
    unsigned short* Wbf = (unsigned short*)((char*)d_ws + WS_WBF_B);

    prep_k<<<1473, 1024, 0, stream>>>(atype, wsi, W, Wbf, actions, Abf, out);
    gemm_k<<<256, 512, 0, stream>>>(Abf, Wbf, bias, out, wsi);
}